// Round 1
// baseline (769.937 us; speedup 1.0000x reference)
//
#include <hip/hip_runtime.h>
#include <cstdint>
#include <cstddef>

#define NUNITS 128000
#define NNEG   8192
#define NROWS  8192
#define NC     1024

typedef unsigned short u16;
typedef float  f32x4  __attribute__((ext_vector_type(4)));
typedef __bf16 bf16x8 __attribute__((ext_vector_type(8)));

__device__ __forceinline__ u16 f2bf(float x) {
    unsigned u = __float_as_uint(x);
    u = (u + 0x7FFFu + ((u >> 16) & 1u)) >> 16;   // round-to-nearest-even
    return (u16)u;
}

// log(expected_count(id)) for the log-uniform (Zipfian) sampler
__device__ __forceinline__ float log_expected_count(int id) {
    float idf = (float)id;
    float p = (logf(idf + 2.0f) - logf(idf + 1.0f)) / logf((float)NUNITS + 1.0f);
    float e = -expm1f((float)NNEG * log1pf(-p));
    return logf(e);
}

// ---------------- K1: cast inputs fp32 -> bf16 ----------------
__global__ void cast_inputs_kernel(const float* __restrict__ in, u16* __restrict__ outp) {
    const int i = blockIdx.x * 256 + threadIdx.x;     // over float4s: 2M total
    const float4 v = ((const float4*)in)[i];
    ushort4 o;
    o.x = f2bf(v.x); o.y = f2bf(v.y); o.z = f2bf(v.z); o.w = f2bf(v.w);
    ((ushort4*)outp)[i] = o;
}

// ---------------- K2: gather sampled rows of kernel -> bf16 [S][C] ----------------
__global__ void gather_w_kernel(const float* __restrict__ kern, const int* __restrict__ sampled,
                                u16* __restrict__ wout) {
    const int srow = blockIdx.x;                       // 8192 blocks
    const int id = sampled[srow];
    const float4* src = (const float4*)(kern + (size_t)id * NC);
    ushort4* dst = (ushort4*)(wout + (size_t)srow * NC);
    const float4 v = src[threadIdx.x];                 // 256 float4 = 1024 floats
    ushort4 o;
    o.x = f2bf(v.x); o.y = f2bf(v.y); o.z = f2bf(v.z); o.w = f2bf(v.w);
    dst[threadIdx.x] = o;
}

// ---------------- K3: b_corr[s] = bias[id] - log(E(id)) ----------------
__global__ void bcorr_kernel(const int* __restrict__ sampled, const float* __restrict__ bias,
                             float* __restrict__ bc) {
    const int i = blockIdx.x * 256 + threadIdx.x;      // 8192
    const int id = sampled[i];
    bc[i] = bias[id] - log_expected_count(id);
}

// ---------------- K4: true logits in fp32 (one wave per row) ----------------
__global__ void true_logits_kernel(const float* __restrict__ inputs, const int* __restrict__ targets,
                                   const float* __restrict__ kern, const float* __restrict__ bias,
                                   float* __restrict__ truel) {
    const int wv = threadIdx.x >> 6;
    const int lane = threadIdx.x & 63;
    const int row = blockIdx.x * 4 + wv;               // grid 2048 x 256
    const int t = targets[row];
    const float4* a = (const float4*)(inputs + (size_t)row * NC);
    const float4* w = (const float4*)(kern + (size_t)t * NC);
    float s = 0.0f;
#pragma unroll
    for (int i = 0; i < 4; ++i) {
        float4 x = a[lane + i * 64];
        float4 y = w[lane + i * 64];
        s += x.x * y.x + x.y * y.y + x.z * y.z + x.w * y.w;
    }
    for (int m = 32; m; m >>= 1) s += __shfl_xor(s, m, 64);
    if (lane == 0) truel[row] = s + bias[t] - log_expected_count(t);
}

// ---------------- K5: fused bf16 MFMA GEMM + partial sum-of-exp ----------------
// C[n][s] = sum_c A[n][c] * W[s][c]; epilogue: exp(C + bcorr[s]) masked on accidental
// hits, reduced per row within the 128x128 tile, written to partial[row][s_chunk].
__global__ __launch_bounds__(256, 2) void gemm_lse_kernel(
    const u16* __restrict__ Abf, const u16* __restrict__ Wbf,
    const float* __restrict__ bcorr, const int* __restrict__ targets,
    const int* __restrict__ sampled, float* __restrict__ partial) {
    __shared__ u16 lds_A[128 * 32];
    __shared__ u16 lds_W[128 * 32];
    __shared__ int   lds_tgt[128];
    __shared__ int   lds_smp[128];
    __shared__ float lds_bc[128];
    __shared__ float lds_rowsum[128];

    const int tid = threadIdx.x;
    const int wv = tid >> 6;            // wave 0..3
    const int lane = tid & 63;
    const int bn0 = blockIdx.x * 128;   // S tile
    const int bm0 = blockIdx.y * 128;   // N tile
    const int wm = (wv >> 1) * 64;      // wave row offset in tile
    const int wn = (wv & 1) * 64;       // wave col offset in tile

    if (tid < 128) {
        lds_tgt[tid] = targets[bm0 + tid];
        lds_smp[tid] = sampled[bn0 + tid];
        lds_bc[tid] = bcorr[bn0 + tid];
        lds_rowsum[tid] = 0.0f;
    }

    f32x4 acc[4][4];
    const f32x4 zero4 = {0.0f, 0.0f, 0.0f, 0.0f};
#pragma unroll
    for (int i = 0; i < 4; ++i)
#pragma unroll
        for (int j = 0; j < 4; ++j) acc[i][j] = zero4;

    // staging geometry: wave wv loads chunks {2wv, 2wv+1} of both tiles.
    // chunk = 16 rows x 32 cols bf16 = 1024 B = 64 lanes x 16 B; lane-contig LDS
    // write matches row-major [128][32] exactly (guide §5 global_load_lds caveat).
    const int c0 = wv * 2;
    const int rsub = lane >> 2;         // 0..15 row-in-chunk
    const int cseg = (lane & 3) * 8;    // bf16 col offset
    const int arow = lane & 15;         // fragment row (m / n)
    const int kq = (lane >> 4) * 8;     // fragment k offset (quad*8)

    for (int kt = 0; kt < NC / 32; ++kt) {
        const int k0 = kt * 32;
#pragma unroll
        for (int c = 0; c < 2; ++c) {
            const int ch = c0 + c;
            const int rl = ch * 16 + rsub;
            const u16* ga = Abf + (size_t)(bm0 + rl) * NC + k0 + cseg;
            const u16* gw = Wbf + (size_t)(bn0 + rl) * NC + k0 + cseg;
            __builtin_amdgcn_global_load_lds(
                (const __attribute__((address_space(1))) void*)ga,
                (__attribute__((address_space(3))) void*)&lds_A[ch * 512], 16, 0, 0);
            __builtin_amdgcn_global_load_lds(
                (const __attribute__((address_space(1))) void*)gw,
                (__attribute__((address_space(3))) void*)&lds_W[ch * 512], 16, 0, 0);
        }
        __syncthreads();   // drains vmcnt for global_load_lds (compiler emits waitcnt)

        bf16x8 af[4], bfv[4];
#pragma unroll
        for (int mt = 0; mt < 4; ++mt)
            af[mt] = *(const bf16x8*)&lds_A[(wm + mt * 16 + arow) * 32 + kq];
#pragma unroll
        for (int nt = 0; nt < 4; ++nt)
            bfv[nt] = *(const bf16x8*)&lds_W[(wn + nt * 16 + arow) * 32 + kq];
#pragma unroll
        for (int mt = 0; mt < 4; ++mt)
#pragma unroll
            for (int nt = 0; nt < 4; ++nt)
                acc[mt][nt] = __builtin_amdgcn_mfma_f32_16x16x32_bf16(
                    af[mt], bfv[nt], acc[mt][nt], 0, 0, 0);
        __syncthreads();   // protect LDS tiles before next-iter staging
    }

    // Epilogue: C/D layout col = lane&15, row = (lane>>4)*4 + reg (verified m89/m91).
#pragma unroll
    for (int mt = 0; mt < 4; ++mt) {
#pragma unroll
        for (int r = 0; r < 4; ++r) {
            const int row_l = wm + mt * 16 + (lane >> 4) * 4 + r;
            const int tg = lds_tgt[row_l];
            float s = 0.0f;
#pragma unroll
            for (int nt = 0; nt < 4; ++nt) {
                const int col_l = wn + nt * 16 + (lane & 15);
                const float logit = acc[mt][nt][r] + lds_bc[col_l];
                // accidental hit: reference subtracts 1e9 -> exp == 0
                s += (lds_smp[col_l] == tg) ? 0.0f : __expf(logit);
            }
            // butterfly over lane bits 0..3: lanes in a quad share rows, differ in cols
#pragma unroll
            for (int m = 1; m < 16; m <<= 1) s += __shfl_xor(s, m, 64);
            if ((lane & 15) == 0) atomicAdd(&lds_rowsum[row_l], s);
        }
    }
    __syncthreads();
    if (tid < 128) partial[(size_t)(bm0 + tid) * 64 + blockIdx.x] = lds_rowsum[tid];
}

// ---------------- K6: per-row logsumexp + block partial loss ----------------
__global__ void row_lse_kernel(const float* __restrict__ partial, const float* __restrict__ truel,
                               float* __restrict__ bsums) {
    const int row = blockIdx.x * 256 + threadIdx.x;    // grid 32 x 256
    const float* p = partial + (size_t)row * 64;
    float s = 0.0f;
#pragma unroll
    for (int i = 0; i < 64; ++i) s += p[i];
    const float tl = truel[row];
    float v = logf(s + expf(tl)) - tl;                 // per-example loss
    for (int m = 32; m; m >>= 1) v += __shfl_xor(v, m, 64);
    __shared__ float red[4];
    if ((threadIdx.x & 63) == 0) red[threadIdx.x >> 6] = v;
    __syncthreads();
    if (threadIdx.x == 0) bsums[blockIdx.x] = red[0] + red[1] + red[2] + red[3];
}

// ---------------- K7: final mean ----------------
__global__ void finalize_kernel(const float* __restrict__ bsums, float* __restrict__ out) {
    float v = (threadIdx.x < 32) ? bsums[threadIdx.x] : 0.0f;
    for (int m = 32; m; m >>= 1) v += __shfl_xor(v, m, 64);
    if (threadIdx.x == 0) out[0] = v / (float)NROWS;
}

extern "C" void kernel_launch(void* const* d_in, const int* in_sizes, int n_in,
                              void* d_out, int out_size, void* d_ws, size_t ws_size,
                              hipStream_t stream) {
    (void)in_sizes; (void)n_in; (void)out_size; (void)ws_size;
    const float* inputs  = (const float*)d_in[0];   // [8192,1024] fp32
    const int*   targets = (const int*)d_in[1];     // [8192]
    const int*   sampled = (const int*)d_in[2];     // [8192]
    const float* kern    = (const float*)d_in[3];   // [128000,1024] fp32
    const float* bias    = (const float*)d_in[4];   // [128000]
    float* out = (float*)d_out;

    char* ws = (char*)d_ws;
    u16* a_bf = (u16*)ws;                                               // 16 MB
    u16* w_bf = (u16*)(ws + (size_t)16 * 1024 * 1024);                  // 16 MB
    float* bc    = (float*)(ws + (size_t)32 * 1024 * 1024);             // 32 KB
    float* truel = (float*)(ws + (size_t)32 * 1024 * 1024 + 32768);     // 32 KB
    float* part  = (float*)(ws + (size_t)32 * 1024 * 1024 + 65536);     // 2 MB
    float* bsums = (float*)(ws + (size_t)32 * 1024 * 1024 + 65536 +
                            (size_t)NROWS * 64 * 4);                    // 128 B

    cast_inputs_kernel<<<dim3(8192), dim3(256), 0, stream>>>(inputs, a_bf);
    gather_w_kernel<<<dim3(8192), dim3(256), 0, stream>>>(kern, sampled, w_bf);
    bcorr_kernel<<<dim3(32), dim3(256), 0, stream>>>(sampled, bias, bc);
    true_logits_kernel<<<dim3(2048), dim3(256), 0, stream>>>(inputs, targets, kern, bias, truel);
    gemm_lse_kernel<<<dim3(64, 64), dim3(256), 0, stream>>>(a_bf, w_bf, bc, targets, sampled, part);
    row_lse_kernel<<<dim3(32), dim3(256), 0, stream>>>(part, truel, bsums);
    finalize_kernel<<<dim3(1), dim3(64), 0, stream>>>(bsums, out);
}